// Round 18
// baseline (34.811 us; speedup 1.0000x reference)
//
#include <hip/hip_runtime.h>

// y = convT3d(x, weight.sum(oc), stride=2, pad=2, k=5) + sum(bias); out = 6^3 stride-6 max.
// MFMA formulation (verified R6-R17, absmax 0.25): y[2m+t] = sum_{ic,abc} x[ic,m+1-abc]*w[ic,t+2abc]
// xT: bf16 [n][q=dpad-1: 16 planes][hpad 34][wpad 34][ic 32]; dpad=0 (zero) not stored.
// R18: conv split along w at the pool boundary (mw 0-14 / 15-29) -> 800 blocks, 9.2KB slabs
//   (1 uint4/thread, contiguous), LDS 18.7KB -> 3 blocks/CU co-resident (vs 1.56) for TLP.
//   Wave core (2-mh-row, 12 ds_read/18 MFMA per active phase) + T1 affinity + T5 setprio kept.

typedef short v8s __attribute__((ext_vector_type(8)));
typedef float v4f __attribute__((ext_vector_type(4)));
typedef unsigned short ushort_t;

#define CHSTR 16384
#define NSTRIDE (32*CHSTR)
#define Y_N 108000
#define Y_TOT (16*Y_N)
#define XSTR 24

#define PLANE_US 36992u          // 34*34*32
#define ROW_US 1088u             // 34*32
#define XTN16 591872u            // per-n xT: 16 planes
#define BT_BYTE_OFF 18939904u    // xT = 16*XTN16*2
#define WSF_BYTE_OFF 18967552u   // +27*64*8*2
#define NEED_MFMA (18967552u + 4097u*4u)

#define SLAB_ROW 576             // LDS slab row stride: 18 cols x 32 ic

static __device__ __forceinline__ ushort_t f2bf(float f) {
  unsigned u = __builtin_bit_cast(unsigned, f);
  unsigned r = (u + 0x7FFFu + ((u >> 16) & 1u)) >> 16;
  return (ushort_t)r;
}

// ---------------- transpose x -> xT bf16 (XCD-affine) + prep (R17 verbatim) --
__global__ __launch_bounds__(576) void transpose_x(const float* __restrict__ x,
                                                   const float* __restrict__ wt,
                                                   const float* __restrict__ bias,
                                                   ushort_t* __restrict__ xT,
                                                   ushort_t* __restrict__ Btab,
                                                   float* __restrict__ wsf) {
  __shared__ __align__(16) float lb[32 * 264];   // [32 ic][8 h8][33 w]
  int b = blockIdx.x, t = threadIdx.x;

  if (b >= 256) {                 // ---- prep path (verified)
    if (t < 256) {
      int abc = b - 256;
      int a = abc / 9, bb = (abc / 3) % 3, c = abc % 3;
      int half = t & 3;
      int l = t >> 2;
      int tt = l & 15, g = l >> 4;
      float v0 = 0.f, v1 = 0.f;
      if (tt < 8) {
        int td = tt & 1, th = (tt >> 1) & 1, tw = tt >> 2;
        int kd = td + 2 * a, kh = th + 2 * bb, kw = tw + 2 * c;
        if (kd < 5 && kh < 5 && kw < 5) {
          int off = kd * 25 + kh * 5 + kw;
          const float* wp0 = wt + (size_t)(8 * g + 2 * half) * 64 * 125 + off;
          const float* wp1 = wp0 + 64 * 125;
          float s0 = 0.f, s1 = 0.f;
#pragma unroll
          for (int oc = 0; oc < 64; ++oc) { s0 += wp0[oc * 125]; s1 += wp1[oc * 125]; }
          v0 = s0; v1 = s1;
        }
      }
      ((unsigned*)Btab)[(abc * 64 + l) * 4 + half] =
          (unsigned)f2bf(v0) | ((unsigned)f2bf(v1) << 16);
      if (abc == 0 && t == 0) {
        float bs = 0.f;
        for (int o = 0; o < 64; ++o) bs += bias[o];
        wsf[4096] = bs;
      }
    }
    return;
  }

  int tn = 2 * (b & 7) + ((b >> 3) & 1);   // home XCD writes its own 2 images
  int q  = b >> 4;
  ushort_t* plane = xT + (size_t)(tn * 16 + q) * PLANE_US;
  const float* xb = x + (size_t)tn * NSTRIDE + q * 1024;

  for (int cc = 0; cc < 4; ++cc) {
    for (int j = 0; j < 4; ++j) {
      int s2 = t + 576 * j;
      if (s2 < 2048) {
        int wq = s2 & 7, h8 = (s2 >> 3) & 7, ic = s2 >> 6;
        int h = 8 * cc - 1 + h8;
        if (h >= 0) {
          float4 v = *(const float4*)&xb[(size_t)ic * CHSTR + h * 32 + wq * 4];
          float* L = lb + ic * 264 + h8 * 33 + wq * 4;
          L[0] = v.x; L[1] = v.y; L[2] = v.z; L[3] = v.w;
        }
      }
    }
    __syncthreads();
    for (int j = 0; j < 2; ++j) {
      int s = t + 576 * j;
      if (s < 1088) {
        int icq = s & 3, qq = s >> 2;
        int wslot = qq % 34, r8 = qq / 34;
        int row = 8 * cc + r8;
        ushort_t o[8];
#pragma unroll
        for (int jj = 0; jj < 8; ++jj) o[jj] = 0;
        if (wslot >= 1 && wslot <= 32 && row > 0) {
          int w2 = wslot - 1;
#pragma unroll
          for (int jj = 0; jj < 8; ++jj)
            o[jj] = f2bf(lb[(8 * icq + jj) * 264 + r8 * 33 + w2]);
        }
        uint4 pk;
        pk.x = (unsigned)o[0] | ((unsigned)o[1] << 16);
        pk.y = (unsigned)o[2] | ((unsigned)o[3] << 16);
        pk.z = (unsigned)o[4] | ((unsigned)o[5] << 16);
        pk.w = (unsigned)o[6] | ((unsigned)o[7] << 16);
        *(uint4*)&plane[(size_t)row * ROW_US + wslot * 32 + icq * 8] = pk;
      }
    }
    __syncthreads();
  }
}

// ---------------- fused MFMA conv + 6^3 pool (w-split, 800 blocks) ------
// blk&7 = xcd owns images {2xcd, 2xcd+1}; j=blk>>3: n-half, OD, OH2, h(w-half).
__global__ __launch_bounds__(576, 7) void conv_mfma8(const ushort_t* __restrict__ xT,
                                                     const ushort_t* __restrict__ Btab,
                                                     const float* __restrict__ wsf,
                                                     float* __restrict__ out) {
  __shared__ __align__(16) char smem[18672];
  ushort_t* As0 = (ushort_t*)smem;                 // 9216 B (8r x 18c x 32ic)
  ushort_t* As1 = (ushort_t*)(smem + 9216);        // 9216 B
  float* ytile  = (float*)smem;                    // 9216 B, overlays As0 (dead at scatter)
  float* red    = (float*)(smem + 18432);          // 240 B

  int blk = blockIdx.x;
  int xcd = blk & 7;
  int j = blk >> 3;                 // 0..99
  int n = 2 * xcd + (j >= 50 ? 1 : 0);
  int c50 = (j >= 50) ? j - 50 : j;
  int OD = c50 / 10;
  int r10 = c50 % 10;
  int OH2 = r10 >> 1, h = r10 & 1;  // h = w-half (mw 15h..15h+14)

  int t = threadIdx.x;
  int wv = t >> 6, l = t & 63;
  int mdl = wv / 3, mhp = wv % 3;
  int tt = l & 15, g = l >> 4;

  const ushort_t* xn = xT + (size_t)n * XTN16;
  // phase-p slab: plane q=3OD+p-1, rows 6OH2..6OH2+7, cols 15h..15h+17
  const ushort_t* slabb = xn + (size_t)(6 * OH2) * ROW_US + 15 * h * 32;
  int r8 = t / 72, inner = t % 72;
  int colrel = inner >> 2, icq = inner & 3;
  size_t soff = (size_t)r8 * ROW_US + colrel * 32 + icq * 8;   // global src offset
  int doff = r8 * SLAB_ROW + colrel * 32 + icq * 8;            // LDS dst offset

  // ---- prologue: plane q = 3OD-1 (q=-1 iff OD==0 -> zero-fill)
  if (OD == 0) {
    *(uint4*)&As0[t * 16 / 2] = make_uint4(0, 0, 0, 0);   // 576 x 16B = 9216B
  } else {
    uint4 v0 = *(const uint4*)(slabb + (size_t)(3 * OD - 1) * PLANE_US + soff);
    *(uint4*)&As0[doff] = v0;
  }
  __syncthreads();

  v4f acc[2];
  acc[0] = (v4f){0.f, 0.f, 0.f, 0.f};
  acc[1] = (v4f){0.f, 0.f, 0.f, 0.f};

  int lane_base = (2 * mhp) * SLAB_ROW + tt * 32 + g * 8;

  for (int p = 0; p < 5; ++p) {
    // ---- T14: issue next plane's load early (plane q = 3OD+p >= 0 always)
    uint4 v0;
    if (p < 4) v0 = *(const uint4*)(slabb + (size_t)(3 * OD + p) * PLANE_US + soff);

    // ---- compute phase p (wave active if a = mdl+2-p in [0,2])
    int a = mdl + 2 - p;
    if (0 <= a && a <= 2) {
      const ushort_t* Ab = (p & 1) ? As1 : As0;
      const ushort_t* Bg = Btab + ((size_t)(a * 9) * 64 + l) * 8;
      __builtin_amdgcn_s_setprio(1);               // T5
#pragma unroll
      for (int c = 0; c < 3; ++c) {
        v8s bv0 = *(const v8s*)(Bg + (0 * 3 + c) * 512);
        v8s bv1 = *(const v8s*)(Bg + (1 * 3 + c) * 512);
        v8s bv2 = *(const v8s*)(Bg + (2 * 3 + c) * 512);
        const ushort_t* ap = Ab + lane_base + (2 - c) * 32;
        v8s a0 = *(const v8s*)(ap);
        v8s a1 = *(const v8s*)(ap + 1 * SLAB_ROW);
        v8s a2 = *(const v8s*)(ap + 2 * SLAB_ROW);
        v8s a3 = *(const v8s*)(ap + 3 * SLAB_ROW);
        // row j feeds (m2=0, b=2-j) and (m2=1, b=3-j)
        acc[0] = __builtin_amdgcn_mfma_f32_16x16x32_bf16(a0, bv2, acc[0], 0, 0, 0);
        acc[0] = __builtin_amdgcn_mfma_f32_16x16x32_bf16(a1, bv1, acc[0], 0, 0, 0);
        acc[0] = __builtin_amdgcn_mfma_f32_16x16x32_bf16(a2, bv0, acc[0], 0, 0, 0);
        acc[1] = __builtin_amdgcn_mfma_f32_16x16x32_bf16(a1, bv2, acc[1], 0, 0, 0);
        acc[1] = __builtin_amdgcn_mfma_f32_16x16x32_bf16(a2, bv1, acc[1], 0, 0, 0);
        acc[1] = __builtin_amdgcn_mfma_f32_16x16x32_bf16(a3, bv0, acc[1], 0, 0, 0);
      }
      __builtin_amdgcn_s_setprio(0);
    }

    // ---- write next plane into other buffer, one barrier
    if (p < 4) {
      ushort_t* dst = (p & 1) ? As0 : As1;
      *(uint4*)&dst[doff] = v0;
      __syncthreads();
    }
  }

  // ---- D scatter to ytile [6odl][12ohl][32w'] (C/D layout verified R6)
  __syncthreads();
  if (tt < 8) {
    int td = tt & 1, th = (tt >> 1) & 1, tw = tt >> 2;
    int odl = 2 * mdl + td;
#pragma unroll
    for (int m2 = 0; m2 < 2; ++m2) {
      int ohl = 2 * (2 * mhp + m2) + th;
      float* yrow = &ytile[(odl * 12 + ohl) * 32];
#pragma unroll
      for (int i = 0; i < 4; ++i) {
        int mwD = 4 * g + i;
        if (mwD < 15) yrow[2 * mwD + tw] = acc[m2][i];
      }
    }
  }
  __syncthreads();

  // ---- pool: 60 threads = (odl 6, p_oh 2, OWloc 5); boxes fully inside w-half
  if (t < 60) {
    int OWloc = t % 5, p_oh = (t / 5) & 1, odl = t / 10;
    float m = -3.4e38f;
    for (int oh = 0; oh < 6; ++oh)
#pragma unroll
      for (int jj = 0; jj < 6; ++jj)
        m = fmaxf(m, ytile[(odl * 12 + 6 * p_oh + oh) * 32 + 6 * OWloc + jj]);
    red[t] = m;
  }
  __syncthreads();
  if (t < 10) {
    int p_oh = t / 5, OWloc = t % 5;
    float m = red[p_oh * 5 + OWloc];
#pragma unroll
    for (int odl = 1; odl < 6; ++odl) m = fmaxf(m, red[odl * 10 + p_oh * 5 + OWloc]);
    out[((n * 5 + OD) * 10 + (2 * OH2 + p_oh)) * 10 + 5 * h + OWloc] = m + wsf[4096];
  }
}

// ================= fallback: R5 verified fp32 path (tiny ws) ===========
__global__ __launch_bounds__(128) void prep2(const float* __restrict__ w,
                                             const float* __restrict__ bias,
                                             float* __restrict__ ws, int woff) {
  int i = blockIdx.x, t = threadIdx.x;
  if (t < 125) {
    const float* wp = w + (size_t)i * 64 * 125 + t;
    float v = 0.f;
#pragma unroll
    for (int o = 0; o < 64; ++o) v += wp[o * 125];
    ws[woff + i * 128 + t] = v;
  }
  if (i == 0 && t == 126) {
    float b = 0.f;
    for (int o = 0; o < 64; ++o) b += bias[o];
    ws[woff + 4096] = b;
  }
}

__global__ __launch_bounds__(256, 4) void conv_stage1(const float* __restrict__ x,
                                                      const float* __restrict__ ws,
                                                      float* part, int woff) {
  __shared__ __align__(16) float xs[170 * XSTR];
  int blk = blockIdx.x;
  int s0 = blk % 320;
  int wq = s0 & 1, hq = (s0 >> 1) & 1, dc = (s0 >> 2) % 5, n = s0 / 20;
  int t = threadIdx.x;
  int mw = t % 15, lmh = t / 15;
  int id_base = 3 * dc - 1, ih_base = 15 * hq - 1;
  int iwb = wq ? 12 : -4;
  int cb = mw + (wq ? 2 : 3);
  const float* xn = x + (size_t)n * NSTRIDE;
  const float* wsw = ws + woff;
  float acc[3][2][2][2] = {{{{0.f}}}};
  for (int phs = 0; phs < 16; ++phs) {
    for (int s = t; s < 1700; s += 256) {
      int c2 = s % 10, row = s / 10;
      int bh = row % 17, q = row / 17;
      int ad = q % 5, lic = q / 5;
      int id = id_base + ad, ih = ih_base + bh, iw = iwb + 2 * c2;
      float2 v = make_float2(0.f, 0.f);
      if ((id | ih | iw) >= 0)
        v = *(const float2*)&xn[(size_t)(phs * 2 + lic) * CHSTR + (id * 32 + ih) * 32 + iw];
      *(float2*)&xs[row * XSTR + 2 * c2] = v;
    }
    __syncthreads();
    if (t < 225) {
#pragma unroll
      for (int lic = 0; lic < 2; ++lic) {
        const float* wc = wsw + (size_t)(phs * 2 + lic) * 128;
        const float* xc = &xs[(lic * 85 + lmh) * XSTR + cb];
        float xv[5][3][3];
#pragma unroll
        for (int a = 0; a < 5; ++a)
#pragma unroll
          for (int b = 0; b < 3; ++b) {
            const float* xr = xc + (a * 17 + b) * XSTR;
            xv[a][b][0] = xr[0]; xv[a][b][1] = xr[1]; xv[a][b][2] = xr[2];
          }
#pragma unroll
        for (int kd = 0; kd < 5; ++kd) {
          constexpr int DT[5] = {0, 1, 0, 1, 0};
          constexpr int AOFF[5] = {2, 2, 1, 1, 0};
          const int dt = DT[kd], aoff = AOFF[kd];
          float wvv[25];
#pragma unroll
          for (int jj = 0; jj < 25; ++jj) wvv[jj] = wc[kd * 25 + jj];
#pragma unroll
          for (int kh = 0; kh < 5; ++kh) {
            constexpr int HT[5] = {0, 1, 0, 1, 0};
            constexpr int BOFF[5] = {2, 2, 1, 1, 0};
            const int ht = HT[kh], boff = BOFF[kh];
#pragma unroll
            for (int m = 0; m < 3; ++m) {
              const float x0 = xv[m + aoff][boff][0];
              const float x1 = xv[m + aoff][boff][1];
              const float x2 = xv[m + aoff][boff][2];
              acc[m][dt][ht][0] += x0 * wvv[kh * 5 + 4];
              acc[m][dt][ht][0] += x1 * wvv[kh * 5 + 2];
              acc[m][dt][ht][0] += x2 * wvv[kh * 5 + 0];
              acc[m][dt][ht][1] += x1 * wvv[kh * 5 + 3];
              acc[m][dt][ht][1] += x2 * wvv[kh * 5 + 1];
            }
          }
        }
      }
    }
    __syncthreads();
  }
  if (t < 225) {
    float* pb = part + (size_t)n * Y_N;
#pragma unroll
    for (int m = 0; m < 3; ++m)
#pragma unroll
      for (int dt = 0; dt < 2; ++dt)
#pragma unroll
        for (int ht = 0; ht < 2; ++ht) {
          int od_g = 6 * dc + 2 * m + dt;
          int oh_g = 30 * hq + 2 * lmh + ht;
          int ow_g = 30 * wq + 2 * mw;
          *(float2*)&pb[(od_g * 60 + oh_g) * 60 + ow_g] =
              make_float2(acc[m][dt][ht][0], acc[m][dt][ht][1]);
        }
  }
}

__global__ __launch_bounds__(256) void pool_stage2(const float* __restrict__ part,
                                                   const float* __restrict__ ws,
                                                   float* __restrict__ out, int woff) {
  __shared__ __align__(16) float buf[2160];
  __shared__ float red[240];
  int blk = blockIdx.x;
  int hc = blk % 10, dc = (blk / 10) % 5, n = blk / 50;
  int t = threadIdx.x;
  const float* pb = part + (size_t)n * Y_N;
  for (int s = t; s < 540; s += 256) {
    int row = s / 15, c4 = s % 15;
    int od = row / 6, oh = row % 6;
    size_t idx = (size_t)((6 * dc + od) * 60 + (6 * hc + oh)) * 60 + 4 * c4;
    *(float4*)&buf[row * 60 + 4 * c4] = *(const float4*)&pb[idx];
  }
  __syncthreads();
  if (t < 240) {
    int wc = t / 24, sub = t % 24;
    float m = -3.4e38f;
#pragma unroll
    for (int k = 0; k < 9; ++k) {
      int e = sub + 24 * k;
      int od = e / 36, r = e % 36;
      int oh = r / 6, ow0 = r % 6;
      m = fmaxf(m, buf[(od * 6 + oh) * 60 + 6 * wc + ow0]);
    }
    red[t] = m;
  }
  __syncthreads();
  if (t < 10) {
    float mm = -3.4e38f;
#pragma unroll
    for (int s2 = 0; s2 < 24; ++s2) mm = fmaxf(mm, red[t * 24 + s2]);
    out[((n * 5 + dc) * 10 + hc) * 10 + t] = mm + ws[woff + 4096];
  }
}

// ---------------- launch ----------------------------------------------
extern "C" void kernel_launch(void* const* d_in, const int* in_sizes, int n_in,
                              void* d_out, int out_size, void* d_ws, size_t ws_size,
                              hipStream_t stream) {
  const float* x    = (const float*)d_in[0];
  const float* w    = (const float*)d_in[1];
  const float* bias = (const float*)d_in[2];
  float* outp = (float*)d_out;

  if (ws_size >= (size_t)NEED_MFMA) {
    ushort_t* xT = (ushort_t*)d_ws;
    ushort_t* Bt = (ushort_t*)((char*)d_ws + BT_BYTE_OFF);
    float* wsf   = (float*)((char*)d_ws + WSF_BYTE_OFF);
    transpose_x<<<256 + 27, 576, 0, stream>>>(x, w, bias, xT, Bt, wsf);
    conv_mfma8<<<800, 576, 0, stream>>>(xT, Bt, wsf, outp);
    return;
  }

  // fp32 fallback (needs ~6.9 MB ws)
  float* ws = (float*)d_ws;
  const size_t need1 = ((size_t)1 * Y_TOT + 4097) * 4;
  if (ws_size >= need1) {
    int woff = Y_TOT;
    prep2<<<32, 128, 0, stream>>>(w, bias, ws, woff);
    conv_stage1<<<320, 256, 0, stream>>>(x, ws, ws, woff);
    pool_stage2<<<800, 256, 0, stream>>>(ws, ws, outp, woff);
  }
}

// Round 19
// 32.040 us; speedup vs baseline: 1.0865x; 1.0865x over previous
//
#include <hip/hip_runtime.h>

// y = convT3d(x, weight.sum(oc), stride=2, pad=2, k=5) + sum(bias); out = 6^3 stride-6 max.
// MFMA formulation (verified R6-R18, absmax 0.25): y[2m+t] = sum_{ic,abc} x[ic,m+1-abc]*w[ic,t+2abc]
//   D[16 w-cells x 8 parities] += A[cells x 32ic] * B[32ic x parities], 27 (a,b,c) chunks.
// xT: bf16 [n][q=dpad-1: 16 planes][hpad 34][wpad 34][ic 32]; dpad=0 (zero) not stored.
// FINAL (= R17, best 32.1us): both kernels XCD-affine (blk&7 = xcd owns images {2xcd,2xcd+1};
//   dispatch model validated R16 +2.8us); conv = R11 core (2-mh-row waves, contiguous slab
//   dbuf, global Btab B-frags) + T5 setprio. Refuted alternatives: direct fp32 staging
//   (R10/R12), single-kernel producer-consumer (R13/R14), conv w-split TLP (R18),
//   occupancy/LDS-read rebalancing (R8/R11 nulls).

typedef short v8s __attribute__((ext_vector_type(8)));
typedef float v4f __attribute__((ext_vector_type(4)));
typedef unsigned short ushort_t;

#define CHSTR 16384
#define NSTRIDE (32*CHSTR)
#define Y_N 108000
#define Y_TOT (16*Y_N)
#define XSTR 24

#define PLANE_US 36992u          // 34*34*32
#define ROW_US 1088u             // 34*32
#define XTN16 591872u            // per-n xT: 16 planes
#define BT_BYTE_OFF 18939904u    // xT = 16*XTN16*2
#define WSF_BYTE_OFF 18967552u   // +27*64*8*2
#define NEED_MFMA (18967552u + 4097u*4u)

static __device__ __forceinline__ ushort_t f2bf(float f) {
  unsigned u = __builtin_bit_cast(unsigned, f);
  unsigned r = (u + 0x7FFFu + ((u >> 16) & 1u)) >> 16;
  return (ushort_t)r;
}

// ---------------- transpose x -> xT bf16 (XCD-affine) + prep ------------
// blocks 0..255: xcd=b&7, tn=2*xcd+((b>>3)&1), q=b>>4 (bijective).
// blocks 256..282: Btab prep unit abc=b-256.
__global__ __launch_bounds__(576) void transpose_x(const float* __restrict__ x,
                                                   const float* __restrict__ wt,
                                                   const float* __restrict__ bias,
                                                   ushort_t* __restrict__ xT,
                                                   ushort_t* __restrict__ Btab,
                                                   float* __restrict__ wsf) {
  __shared__ __align__(16) float lb[32 * 264];   // [32 ic][8 h8][33 w] = 33792 B
  int b = blockIdx.x, t = threadIdx.x;

  if (b >= 256) {                 // ---- prep path (verified R10/R12 body)
    if (t < 256) {
      int abc = b - 256;
      int a = abc / 9, bb = (abc / 3) % 3, c = abc % 3;
      int half = t & 3;
      int l = t >> 2;
      int tt = l & 15, g = l >> 4;
      float v0 = 0.f, v1 = 0.f;
      if (tt < 8) {
        int td = tt & 1, th = (tt >> 1) & 1, tw = tt >> 2;
        int kd = td + 2 * a, kh = th + 2 * bb, kw = tw + 2 * c;
        if (kd < 5 && kh < 5 && kw < 5) {
          int off = kd * 25 + kh * 5 + kw;
          const float* wp0 = wt + (size_t)(8 * g + 2 * half) * 64 * 125 + off;
          const float* wp1 = wp0 + 64 * 125;
          float s0 = 0.f, s1 = 0.f;
#pragma unroll
          for (int oc = 0; oc < 64; ++oc) { s0 += wp0[oc * 125]; s1 += wp1[oc * 125]; }
          v0 = s0; v1 = s1;
        }
      }
      ((unsigned*)Btab)[(abc * 64 + l) * 4 + half] =
          (unsigned)f2bf(v0) | ((unsigned)f2bf(v1) << 16);
      if (abc == 0 && t == 0) {
        float bs = 0.f;
        for (int o = 0; o < 64; ++o) bs += bias[o];
        wsf[4096] = bs;
      }
    }
    return;
  }

  // T1 write-side: home XCD (b&7) writes its own 2 images.
  int tn = 2 * (b & 7) + ((b >> 3) & 1);
  int q  = b >> 4;                // plane q <-> dpad q+1, real d = q
  ushort_t* plane = xT + (size_t)(tn * 16 + q) * PLANE_US;
  const float* xb = x + (size_t)tn * NSTRIDE + q * 1024;

  for (int cc = 0; cc < 4; ++cc) {
    // ---- stage fp32: rows h = 8cc-1+h8 (h=-1 only cc=0,h8=0)
    for (int j = 0; j < 4; ++j) {
      int s2 = t + 576 * j;
      if (s2 < 2048) {
        int wq = s2 & 7, h8 = (s2 >> 3) & 7, ic = s2 >> 6;
        int h = 8 * cc - 1 + h8;
        if (h >= 0) {
          float4 v = *(const float4*)&xb[(size_t)ic * CHSTR + h * 32 + wq * 4];
          float* L = lb + ic * 264 + h8 * 33 + wq * 4;
          L[0] = v.x; L[1] = v.y; L[2] = v.z; L[3] = v.w;
        }
      }
    }
    __syncthreads();
    // ---- emit bf16 rows 8cc..8cc+7 (row 0 = h=-1 -> zeros; wslot 0,33 -> zeros)
    for (int j = 0; j < 2; ++j) {
      int s = t + 576 * j;
      if (s < 1088) {
        int icq = s & 3, qq = s >> 2;
        int wslot = qq % 34, r8 = qq / 34;
        int row = 8 * cc + r8;
        ushort_t o[8];
#pragma unroll
        for (int jj = 0; jj < 8; ++jj) o[jj] = 0;
        if (wslot >= 1 && wslot <= 32 && row > 0) {
          int w2 = wslot - 1;
#pragma unroll
          for (int jj = 0; jj < 8; ++jj)
            o[jj] = f2bf(lb[(8 * icq + jj) * 264 + r8 * 33 + w2]);
        }
        uint4 pk;
        pk.x = (unsigned)o[0] | ((unsigned)o[1] << 16);
        pk.y = (unsigned)o[2] | ((unsigned)o[3] << 16);
        pk.z = (unsigned)o[4] | ((unsigned)o[5] << 16);
        pk.w = (unsigned)o[6] | ((unsigned)o[7] << 16);
        *(uint4*)&plane[(size_t)row * ROW_US + wslot * 32 + icq * 8] = pk;
      }
    }
    __syncthreads();
  }
}

// ---------------- fused MFMA conv + 6^3 pool (R11 core + T1/T5) ---------
// 400 blocks; decode: xcd = blk&7 owns images {2*xcd, 2*xcd+1} (L2 affinity).
__global__ __launch_bounds__(576, 7) void conv_mfma6(const ushort_t* __restrict__ xT,
                                                     const ushort_t* __restrict__ Btab,
                                                     const float* __restrict__ wsf,
                                                     float* __restrict__ out) {
  __shared__ __align__(16) char smem[35328];
  ushort_t* As0 = (ushort_t*)smem;                 // 17408 B (8r x 34c x 32ic)
  ushort_t* As1 = (ushort_t*)(smem + 17408);       // 17408 B
  float* ytile  = (float*)smem;                    // overlays dead A-bufs
  float* red    = (float*)(smem + 34816);          // 480 B

  int blk = blockIdx.x;
  // T1: round-robin dispatch -> blk&7 = XCD. Each XCD gets 2 whole images.
  int xcd = blk & 7;
  int j = blk >> 3;                 // 0..49
  int n = 2 * xcd + (j >= 25 ? 1 : 0);
  int cell = (j >= 25) ? j - 25 : j;
  int OD = cell / 5, OH2 = cell % 5;

  int t = threadIdx.x;
  int wv = t >> 6, l = t & 63;
  int mdl = wv / 3, mhp = wv % 3;
  int tt = l & 15, g = l >> 4;

  const ushort_t* xn = xT + (size_t)n * XTN16;
  int rowoff = 6 * OH2 * (int)ROW_US;

  // ---- prologue: plane q = 3OD-1 (q=-1 iff OD==0 -> zero-fill)
  if (OD == 0) {
    for (int jj = 0; jj < 2; ++jj) {
      int s = t + 576 * jj;
      if (s < 1088) *(uint4*)&As0[s * 8] = make_uint4(0, 0, 0, 0);
    }
  } else {
    const ushort_t* slab = xn + (size_t)(3 * OD - 1) * PLANE_US + rowoff;
    uint4 v0 = *(const uint4*)(slab + (size_t)t * 8);
    uint4 v1;
    if (t < 512) v1 = *(const uint4*)(slab + (size_t)(t + 576) * 8);
    *(uint4*)&As0[t * 8] = v0;
    if (t < 512) *(uint4*)&As0[(t + 576) * 8] = v1;
  }
  __syncthreads();

  v4f acc[2][2];
#pragma unroll
  for (int m2 = 0; m2 < 2; ++m2)
#pragma unroll
    for (int wh = 0; wh < 2; ++wh) acc[m2][wh] = (v4f){0.f, 0.f, 0.f, 0.f};

  int lane_base = (2 * mhp) * ROW_US + tt * 32 + g * 8;

  for (int p = 0; p < 5; ++p) {
    // ---- T14: issue next plane's loads early (plane q = 3OD+p >= 0 always)
    uint4 v0, v1;
    if (p < 4) {
      const ushort_t* slab = xn + (size_t)(3 * OD + p) * PLANE_US + rowoff;
      v0 = *(const uint4*)(slab + (size_t)t * 8);
      if (t < 512) v1 = *(const uint4*)(slab + (size_t)(t + 576) * 8);
    }

    // ---- compute phase p (wave active if a = mdl+2-p in [0,2])
    int a = mdl + 2 - p;
    if (0 <= a && a <= 2) {
      const ushort_t* Ab = (p & 1) ? As1 : As0;
      const ushort_t* Bg = Btab + ((size_t)(a * 9) * 64 + l) * 8;
      __builtin_amdgcn_s_setprio(1);               // T5: favor MFMA waves
#pragma unroll
      for (int c = 0; c < 3; ++c) {
        v8s bv0 = *(const v8s*)(Bg + (0 * 3 + c) * 512);
        v8s bv1 = *(const v8s*)(Bg + (1 * 3 + c) * 512);
        v8s bv2 = *(const v8s*)(Bg + (2 * 3 + c) * 512);
#pragma unroll
        for (int wh = 0; wh < 2; ++wh) {
          const ushort_t* ap = Ab + lane_base + (2 - c + 16 * wh) * 32;
          v8s a0 = *(const v8s*)(ap);
          v8s a1 = *(const v8s*)(ap + 1 * ROW_US);
          v8s a2 = *(const v8s*)(ap + 2 * ROW_US);
          v8s a3 = *(const v8s*)(ap + 3 * ROW_US);
          // row j feeds (m2=0, b=2-j) and (m2=1, b=3-j)
          acc[0][wh] = __builtin_amdgcn_mfma_f32_16x16x32_bf16(a0, bv2, acc[0][wh], 0, 0, 0);
          acc[0][wh] = __builtin_amdgcn_mfma_f32_16x16x32_bf16(a1, bv1, acc[0][wh], 0, 0, 0);
          acc[0][wh] = __builtin_amdgcn_mfma_f32_16x16x32_bf16(a2, bv0, acc[0][wh], 0, 0, 0);
          acc[1][wh] = __builtin_amdgcn_mfma_f32_16x16x32_bf16(a1, bv2, acc[1][wh], 0, 0, 0);
          acc[1][wh] = __builtin_amdgcn_mfma_f32_16x16x32_bf16(a2, bv1, acc[1][wh], 0, 0, 0);
          acc[1][wh] = __builtin_amdgcn_mfma_f32_16x16x32_bf16(a3, bv0, acc[1][wh], 0, 0, 0);
        }
      }
      __builtin_amdgcn_s_setprio(0);
    }

    // ---- write next plane into other buffer, one barrier
    if (p < 4) {
      ushort_t* dst = (p & 1) ? As0 : As1;
      *(uint4*)&dst[t * 8] = v0;
      if (t < 512) *(uint4*)&dst[(t + 576) * 8] = v1;
      __syncthreads();
    }
  }

  // ---- D scatter to ytile (C/D layout verified R6)
  __syncthreads();
  if (tt < 8) {
    int td = tt & 1, th = (tt >> 1) & 1, tw = tt >> 2;
    int odl = 2 * mdl + td;
#pragma unroll
    for (int m2 = 0; m2 < 2; ++m2) {
      int ohl = 2 * (2 * mhp + m2) + th;
      float* yrow = &ytile[(odl * 12 + ohl) * 64];
#pragma unroll
      for (int wh = 0; wh < 2; ++wh)
#pragma unroll
        for (int i = 0; i < 4; ++i)
          yrow[2 * (16 * wh + 4 * g + i) + tw] = acc[m2][wh][i];
    }
  }
  __syncthreads();

  // ---- 6^3 pool: 120 threads = (odl 6, p_oh 2, OW 10)
  if (t < 120) {
    int OW = t % 10, p_oh = (t / 10) & 1, odl = t / 20;
    float m = -3.4e38f;
    for (int oh = 0; oh < 6; ++oh)
#pragma unroll
      for (int jj = 0; jj < 6; ++jj)
        m = fmaxf(m, ytile[(odl * 12 + 6 * p_oh + oh) * 64 + 6 * OW + jj]);
    red[t] = m;
  }
  __syncthreads();
  if (t < 20) {
    int OW = t % 10, p_oh = t / 10;
    float m = red[p_oh * 10 + OW];
#pragma unroll
    for (int odl = 1; odl < 6; ++odl) m = fmaxf(m, red[odl * 20 + p_oh * 10 + OW]);
    out[((n * 5 + OD) * 10 + (2 * OH2 + p_oh)) * 10 + OW] = m + wsf[4096];
  }
}

// ================= fallback: R5 verified fp32 path (tiny ws) ===========
__global__ __launch_bounds__(128) void prep2(const float* __restrict__ w,
                                             const float* __restrict__ bias,
                                             float* __restrict__ ws, int woff) {
  int i = blockIdx.x, t = threadIdx.x;
  if (t < 125) {
    const float* wp = w + (size_t)i * 64 * 125 + t;
    float v = 0.f;
#pragma unroll
    for (int o = 0; o < 64; ++o) v += wp[o * 125];
    ws[woff + i * 128 + t] = v;
  }
  if (i == 0 && t == 126) {
    float b = 0.f;
    for (int o = 0; o < 64; ++o) b += bias[o];
    ws[woff + 4096] = b;
  }
}

__global__ __launch_bounds__(256, 4) void conv_stage1(const float* __restrict__ x,
                                                      const float* __restrict__ ws,
                                                      float* part, int woff) {
  __shared__ __align__(16) float xs[170 * XSTR];
  int blk = blockIdx.x;
  int s0 = blk % 320;
  int wq = s0 & 1, hq = (s0 >> 1) & 1, dc = (s0 >> 2) % 5, n = s0 / 20;
  int t = threadIdx.x;
  int mw = t % 15, lmh = t / 15;
  int id_base = 3 * dc - 1, ih_base = 15 * hq - 1;
  int iwb = wq ? 12 : -4;
  int cb = mw + (wq ? 2 : 3);
  const float* xn = x + (size_t)n * NSTRIDE;
  const float* wsw = ws + woff;
  float acc[3][2][2][2] = {{{{0.f}}}};
  for (int phs = 0; phs < 16; ++phs) {
    for (int s = t; s < 1700; s += 256) {
      int c2 = s % 10, row = s / 10;
      int bh = row % 17, q = row / 17;
      int ad = q % 5, lic = q / 5;
      int id = id_base + ad, ih = ih_base + bh, iw = iwb + 2 * c2;
      float2 v = make_float2(0.f, 0.f);
      if ((id | ih | iw) >= 0)
        v = *(const float2*)&xn[(size_t)(phs * 2 + lic) * CHSTR + (id * 32 + ih) * 32 + iw];
      *(float2*)&xs[row * XSTR + 2 * c2] = v;
    }
    __syncthreads();
    if (t < 225) {
#pragma unroll
      for (int lic = 0; lic < 2; ++lic) {
        const float* wc = wsw + (size_t)(phs * 2 + lic) * 128;
        const float* xc = &xs[(lic * 85 + lmh) * XSTR + cb];
        float xv[5][3][3];
#pragma unroll
        for (int a = 0; a < 5; ++a)
#pragma unroll
          for (int b = 0; b < 3; ++b) {
            const float* xr = xc + (a * 17 + b) * XSTR;
            xv[a][b][0] = xr[0]; xv[a][b][1] = xr[1]; xv[a][b][2] = xr[2];
          }
#pragma unroll
        for (int kd = 0; kd < 5; ++kd) {
          constexpr int DT[5] = {0, 1, 0, 1, 0};
          constexpr int AOFF[5] = {2, 2, 1, 1, 0};
          const int dt = DT[kd], aoff = AOFF[kd];
          float wvv[25];
#pragma unroll
          for (int jj = 0; jj < 25; ++jj) wvv[jj] = wc[kd * 25 + jj];
#pragma unroll
          for (int kh = 0; kh < 5; ++kh) {
            constexpr int HT[5] = {0, 1, 0, 1, 0};
            constexpr int BOFF[5] = {2, 2, 1, 1, 0};
            const int ht = HT[kh], boff = BOFF[kh];
#pragma unroll
            for (int m = 0; m < 3; ++m) {
              const float x0 = xv[m + aoff][boff][0];
              const float x1 = xv[m + aoff][boff][1];
              const float x2 = xv[m + aoff][boff][2];
              acc[m][dt][ht][0] += x0 * wvv[kh * 5 + 4];
              acc[m][dt][ht][0] += x1 * wvv[kh * 5 + 2];
              acc[m][dt][ht][0] += x2 * wvv[kh * 5 + 0];
              acc[m][dt][ht][1] += x1 * wvv[kh * 5 + 3];
              acc[m][dt][ht][1] += x2 * wvv[kh * 5 + 1];
            }
          }
        }
      }
    }
    __syncthreads();
  }
  if (t < 225) {
    float* pb = part + (size_t)n * Y_N;
#pragma unroll
    for (int m = 0; m < 3; ++m)
#pragma unroll
      for (int dt = 0; dt < 2; ++dt)
#pragma unroll
        for (int ht = 0; ht < 2; ++ht) {
          int od_g = 6 * dc + 2 * m + dt;
          int oh_g = 30 * hq + 2 * lmh + ht;
          int ow_g = 30 * wq + 2 * mw;
          *(float2*)&pb[(od_g * 60 + oh_g) * 60 + ow_g] =
              make_float2(acc[m][dt][ht][0], acc[m][dt][ht][1]);
        }
  }
}

__global__ __launch_bounds__(256) void pool_stage2(const float* __restrict__ part,
                                                   const float* __restrict__ ws,
                                                   float* __restrict__ out, int woff) {
  __shared__ __align__(16) float buf[2160];
  __shared__ float red[240];
  int blk = blockIdx.x;
  int hc = blk % 10, dc = (blk / 10) % 5, n = blk / 50;
  int t = threadIdx.x;
  const float* pb = part + (size_t)n * Y_N;
  for (int s = t; s < 540; s += 256) {
    int row = s / 15, c4 = s % 15;
    int od = row / 6, oh = row % 6;
    size_t idx = (size_t)((6 * dc + od) * 60 + (6 * hc + oh)) * 60 + 4 * c4;
    *(float4*)&buf[row * 60 + 4 * c4] = *(const float4*)&pb[idx];
  }
  __syncthreads();
  if (t < 240) {
    int wc = t / 24, sub = t % 24;
    float m = -3.4e38f;
#pragma unroll
    for (int k = 0; k < 9; ++k) {
      int e = sub + 24 * k;
      int od = e / 36, r = e % 36;
      int oh = r / 6, ow0 = r % 6;
      m = fmaxf(m, buf[(od * 6 + oh) * 60 + 6 * wc + ow0]);
    }
    red[t] = m;
  }
  __syncthreads();
  if (t < 10) {
    float mm = -3.4e38f;
#pragma unroll
    for (int s2 = 0; s2 < 24; ++s2) mm = fmaxf(mm, red[t * 24 + s2]);
    out[((n * 5 + dc) * 10 + hc) * 10 + t] = mm + ws[woff + 4096];
  }
}

// ---------------- launch ----------------------------------------------
extern "C" void kernel_launch(void* const* d_in, const int* in_sizes, int n_in,
                              void* d_out, int out_size, void* d_ws, size_t ws_size,
                              hipStream_t stream) {
  const float* x    = (const float*)d_in[0];
  const float* w    = (const float*)d_in[1];
  const float* bias = (const float*)d_in[2];
  float* outp = (float*)d_out;

  if (ws_size >= (size_t)NEED_MFMA) {
    ushort_t* xT = (ushort_t*)d_ws;
    ushort_t* Bt = (ushort_t*)((char*)d_ws + BT_BYTE_OFF);
    float* wsf   = (float*)((char*)d_ws + WSF_BYTE_OFF);
    transpose_x<<<256 + 27, 576, 0, stream>>>(x, w, bias, xT, Bt, wsf);
    conv_mfma6<<<400, 576, 0, stream>>>(xT, Bt, wsf, outp);
    return;
  }

  // fp32 fallback (needs ~6.9 MB ws)
  float* ws = (float*)d_ws;
  const size_t need1 = ((size_t)1 * Y_TOT + 4097) * 4;
  if (ws_size >= need1) {
    int woff = Y_TOT;
    prep2<<<32, 128, 0, stream>>>(w, bias, ws, woff);
    conv_stage1<<<320, 256, 0, stream>>>(x, ws, ws, woff);
    pool_stage2<<<800, 256, 0, stream>>>(ws, ws, outp, woff);
  }
}